// Round 11
// baseline (105.873 us; speedup 1.0000x reference)
//
#include <hip/hip_runtime.h>

#define B_TOTAL 131072
#define NF 32
#define NA 8
#define NH 64

using frag_ab = __attribute__((ext_vector_type(8))) short;   // 8 bf16 (4 VGPRs)
using f32x16  = __attribute__((ext_vector_type(16))) float;  // 32x32 accumulator
typedef int   v2i __attribute__((ext_vector_type(2)));
typedef float v2f __attribute__((ext_vector_type(2)));

__device__ __forceinline__ unsigned short f2bf(float x) {
  unsigned u = __float_as_uint(x);
  u = (u + 0x7FFFu + ((u >> 16) & 1u)) >> 16;   // RNE
  return (unsigned short)u;
}

// ---- one prep kernel, three jobs by blockIdx range (all R5/R9/R10-verified formulas) ----
#define PW1_BLOCKS 384     // 98304 elems
#define PW2_BLOCKS 16      // 4096 elems
#define FA2_BLOCKS 24576   // 6291456 elems
__global__ void prep_kernel(const float* __restrict__ W1, const float* __restrict__ b1,
                            const float* __restrict__ W2,
                            const float* __restrict__ ft, const float* __restrict__ at,
                            unsigned short* __restrict__ w1p, float* __restrict__ w2p,
                            unsigned short* __restrict__ fa2) {
  const int bid = blockIdx.x;
  const int t = threadIdx.x;
  if (bid < PW1_BLOCKS) {
    // w1p[((f*6 + ht*3 + kt)*64 + l)*8 + j]; h = ht*32+(l&31), i = kt*16+(l>>5)*8+j
    int idx = bid * 256 + t;
    int j = idx & 7, l = (idx >> 3) & 63, tq = idx >> 9;
    int q = tq % 6, f = tq / 6;
    int ht = q / 3, kt = q % 3;
    int h = ht * 32 + (l & 31);
    int i = kt * 16 + ((l >> 5) << 3) + j;
    float v = 0.0f;
    if (i < NF + NA)       v = W1[(f * (NF + NA) + i) * NH + h];
    else if (i == NF + NA) v = b1[f * NH + h];
    w1p[idx] = f2bf(v);
  } else if (bid < PW1_BLOCKS + PW2_BLOCKS) {
    // w2p[((f*2+g)*2+ht)*16 + r] = W2[f][ht*32 + (r&3) + 8*(r>>2) + 4*g]
    int idx = (bid - PW1_BLOCKS) * 256 + t;
    int r = idx & 15, ht = (idx >> 4) & 1, g = (idx >> 5) & 1, f = idx >> 6;
    w2p[idx] = W2[f * NH + ht * 32 + (r & 3) + 8 * (r >> 2) + 4 * g];
  } else {
    // fa2[((bt*3+kt)*64+l)*8+j]: b = bt*32+(l&31), g = l>>5
    int idx = (bid - PW1_BLOCKS - PW2_BLOCKS) * 256 + t;
    int j = idx & 7;
    int l = (idx >> 3) & 63;
    int rest = idx >> 9;
    int kt = rest % 3;
    long bt = rest / 3;
    int g = l >> 5, lc = l & 31;
    long b = bt * 32 + lc;
    unsigned short o;
    if (kt < 2)       o = f2bf(ft[b * NF + kt * 16 + g * 8 + j]);
    else if (g == 0)  o = f2bf(at[b * NA + j]);
    else              o = (j == 0) ? (unsigned short)0x3F80 : (unsigned short)0;
    fa2[idx] = o;
  }
}

__device__ __forceinline__ v2f pk_fma(v2f a, v2f b, v2f c) {   // R5/R6/R9/R10-verified
  v2f d;
  asm("v_pk_fma_f32 %0, %1, %2, %3" : "=v"(d) : "v"(a), "v"(b), "v"(c));
  return d;
}

__device__ __forceinline__ float xor32_add(float v) {   // R4/R5/R6/R9/R10-verified
  v2i p = __builtin_amdgcn_permlane32_swap(__float_as_int(v), __float_as_int(v), false, false);
  return __int_as_float(p.x) + __int_as_float(p.y);
}

// f-outer, zero-LDS/zero-barrier; all weights in registers; direct out write (+b2+skip).
__global__ __launch_bounds__(256, 3) void fused_mlp_kernel(
    const unsigned short* __restrict__ fa2, const unsigned short* __restrict__ w1p,
    const float* __restrict__ w2p, const float* __restrict__ b2,
    const float* __restrict__ ft, float* __restrict__ out) {
  const int t = threadIdx.x;
  const int wv = t >> 6;
  const int l = t & 63;
  const int g = l >> 5;
  const int lc = l & 31;
  const int gf = blockIdx.x >> 7;        // f-pair 0..15
  const int nb = blockIdx.x & 127;       // b-range; XCD = nb%8 for all gf -> L2 reuse + write coalesce

  // ---- prologue: ALL weights -> registers, once ----
  frag_ab wf[2][2][3];   // layer-1 A-frags (48 VGPR)
#pragma unroll
  for (int f2 = 0; f2 < 2; ++f2)
#pragma unroll
    for (int ht = 0; ht < 2; ++ht)
#pragma unroll
      for (int kt = 0; kt < 3; ++kt)
        wf[f2][ht][kt] = *(const frag_ab*)(w1p + ((((gf * 2 + f2) * 6 + ht * 3 + kt) * 64 + l) * 8));

  float4 wq[2][8];       // layer-2 weights hoisted (64 VGPR) — kills in-loop VMEM latency
#pragma unroll
  for (int f2 = 0; f2 < 2; ++f2) {
    const float4* wp2 = (const float4*)w2p + ((gf * 2 + f2) * 2 + g) * 8;
#pragma unroll
    for (int q = 0; q < 8; ++q) wq[f2][q] = wp2[q];
  }

  float2 b2v = *(const float2*)(b2 + gf * 2);

  const f32x16 zero16 = {0.f,0.f,0.f,0.f,0.f,0.f,0.f,0.f,0.f,0.f,0.f,0.f,0.f,0.f,0.f,0.f};
  const long bt0 = (long)nb * 32 + wv * 8;

  frag_ab cur[3], nxt[3];
#pragma unroll
  for (int kt = 0; kt < 3; ++kt)
    cur[kt] = *(const frag_ab*)(fa2 + ((bt0 * 3 + kt) * 64 + l) * 8);

#pragma unroll
  for (int it = 0; it < 8; ++it) {
    if (it < 7) {   // 1-deep prefetch (L2-resident; latency < per-it compute)
#pragma unroll
      for (int kt = 0; kt < 3; ++kt)
        nxt[kt] = *(const frag_ab*)(fa2 + (((bt0 + it + 1) * 3 + kt) * 64 + l) * 8);
    }

    float resv[2];
#pragma unroll
    for (int f2 = 0; f2 < 2; ++f2) {
      f32x16 a0 = zero16, a1 = zero16;
#pragma unroll
      for (int kt = 0; kt < 3; ++kt) {
        a0 = __builtin_amdgcn_mfma_f32_32x32x16_bf16(wf[f2][0][kt], cur[kt], a0, 0, 0, 0);
        a1 = __builtin_amdgcn_mfma_f32_32x32x16_bf16(wf[f2][1][kt], cur[kt], a1, 0, 0, 0);
      }
      // layer 2: relu + dot(W2), 4 independent pk_fma chains (depth 4 each)
      v2f psA = {0.f,0.f}, psB = {0.f,0.f}, psC = {0.f,0.f}, psD = {0.f,0.f};
#pragma unroll
      for (int rq = 0; rq < 4; ++rq) {
        float4 w0 = wq[f2][rq], w1 = wq[f2][4 + rq];
        v2f m;
        m[0] = fmaxf(a0[rq * 4 + 0], 0.f); m[1] = fmaxf(a0[rq * 4 + 1], 0.f);
        if (rq & 1) psB = pk_fma(m, (v2f){w0.x, w0.y}, psB);
        else        psA = pk_fma(m, (v2f){w0.x, w0.y}, psA);
        m[0] = fmaxf(a0[rq * 4 + 2], 0.f); m[1] = fmaxf(a0[rq * 4 + 3], 0.f);
        if (rq & 1) psB = pk_fma(m, (v2f){w0.z, w0.w}, psB);
        else        psA = pk_fma(m, (v2f){w0.z, w0.w}, psA);
        m[0] = fmaxf(a1[rq * 4 + 0], 0.f); m[1] = fmaxf(a1[rq * 4 + 1], 0.f);
        if (rq & 1) psD = pk_fma(m, (v2f){w1.x, w1.y}, psD);
        else        psC = pk_fma(m, (v2f){w1.x, w1.y}, psC);
        m[0] = fmaxf(a1[rq * 4 + 2], 0.f); m[1] = fmaxf(a1[rq * 4 + 3], 0.f);
        if (rq & 1) psD = pk_fma(m, (v2f){w1.z, w1.w}, psD);
        else        psC = pk_fma(m, (v2f){w1.z, w1.w}, psC);
      }
      v2f ts = (psA + psB) + (psC + psD);
      resv[f2] = xor32_add(ts[0] + ts[1]);
    }

    // direct out write (+b2 +skip); 8B/lane, same-XCD line completion in L2
    if (g == 0) {
      const long b = (bt0 + it) * 32 + lc;
      float2 x = *(const float2*)(ft + b * NF + gf * 2);
      float2 o;
      o.x = resv[0] + b2v.x + x.x;
      o.y = resv[1] + b2v.y + x.y;
      *(float2*)(out + b * NF + gf * 2) = o;
    }

#pragma unroll
    for (int kt = 0; kt < 3; ++kt) cur[kt] = nxt[kt];
  }
}

extern "C" void kernel_launch(void* const* d_in, const int* in_sizes, int n_in,
                              void* d_out, int out_size, void* d_ws, size_t ws_size,
                              hipStream_t stream) {
  const float* ft = (const float*)d_in[0];
  const float* at = (const float*)d_in[1];
  const float* W1 = (const float*)d_in[2];
  const float* b1 = (const float*)d_in[3];
  const float* W2 = (const float*)d_in[4];
  const float* b2 = (const float*)d_in[5];
  float* out = (float*)d_out;

  unsigned short* w1p = (unsigned short*)d_ws;                       // 192 KB
  float* w2p = (float*)((char*)d_ws + (1u << 18));                   // 16 KB  @ 256 KB
  unsigned short* fa2 = (unsigned short*)((char*)d_ws + (1u << 19)); // 12.6 MB @ 512 KB

  prep_kernel<<<PW1_BLOCKS + PW2_BLOCKS + FA2_BLOCKS, 256, 0, stream>>>(
      W1, b1, W2, ft, at, w1p, w2p, fa2);
  fused_mlp_kernel<<<2048, 256, 0, stream>>>(fa2, w1p, w2p, b2, ft, out);
}

// Round 12
// 82.567 us; speedup vs baseline: 1.2823x; 1.2823x over previous
//
#include <hip/hip_runtime.h>

#define B_TOTAL 131072
#define NF 32
#define NA 8
#define NH 64

using frag_ab = __attribute__((ext_vector_type(8))) short;   // 8 bf16 (4 VGPRs)
using f32x16  = __attribute__((ext_vector_type(16))) float;  // 32x32 accumulator
typedef int   v2i __attribute__((ext_vector_type(2)));
typedef float v2f __attribute__((ext_vector_type(2)));

__device__ __forceinline__ unsigned short f2bf(float x) {
  unsigned u = __float_as_uint(x);
  u = (u + 0x7FFFu + ((u >> 16) & 1u)) >> 16;   // RNE
  return (unsigned short)u;
}

// ---- one prep kernel, three jobs by blockIdx range ----
// w1p/w2p formulas R5/R9/R10/R11-verified (unchanged). fa2 formula R10/R11-verified,
// re-threaded: one thread per 8-elem fragment (16B write, 32B read) for coalescing.
#define PW1_BLOCKS 384     // 98304 elems
#define PW2_BLOCKS 16      // 4096 elems
#define FA2_BLOCKS 3072    // 786432 frags ( (B/32)*3*64 )
__global__ void prep_kernel(const float* __restrict__ W1, const float* __restrict__ b1,
                            const float* __restrict__ W2,
                            const float* __restrict__ ft, const float* __restrict__ at,
                            unsigned short* __restrict__ w1p, float* __restrict__ w2p,
                            unsigned short* __restrict__ fa2) {
  const int bid = blockIdx.x;
  const int t = threadIdx.x;
  if (bid < FA2_BLOCKS) {
    // frag id = (bt*3 + kt)*64 + l ; writes fa2[fid*8 .. fid*8+8)
    int fid = bid * 256 + t;
    int l = fid & 63;
    int rest = fid >> 6;
    int kt = rest % 3;
    long bt = rest / 3;
    int g = l >> 5, lc = l & 31;
    long b = bt * 32 + lc;
    frag_ab o;
    if (kt < 2) {
      float tmp[8];
      *(float4*)tmp       = *(const float4*)(ft + b * NF + kt * 16 + g * 8);
      *(float4*)(tmp + 4) = *(const float4*)(ft + b * NF + kt * 16 + g * 8 + 4);
#pragma unroll
      for (int j = 0; j < 8; ++j) o[j] = (short)f2bf(tmp[j]);
    } else if (g == 0) {
      float tmp[8];
      *(float4*)tmp       = *(const float4*)(at + b * NA);
      *(float4*)(tmp + 4) = *(const float4*)(at + b * NA + 4);
#pragma unroll
      for (int j = 0; j < 8; ++j) o[j] = (short)f2bf(tmp[j]);
    } else {
#pragma unroll
      for (int j = 0; j < 8; ++j) o[j] = (short)((j == 0) ? 0x3F80 : 0);
    }
    *(frag_ab*)(fa2 + (long)fid * 8) = o;
  } else if (bid < FA2_BLOCKS + PW1_BLOCKS) {
    int idx = (bid - FA2_BLOCKS) * 256 + t;
    int j = idx & 7, l = (idx >> 3) & 63, tq = idx >> 9;
    int q = tq % 6, f = tq / 6;
    int ht = q / 3, kt = q % 3;
    int h = ht * 32 + (l & 31);
    int i = kt * 16 + ((l >> 5) << 3) + j;
    float v = 0.0f;
    if (i < NF + NA)       v = W1[(f * (NF + NA) + i) * NH + h];
    else if (i == NF + NA) v = b1[f * NH + h];
    w1p[idx] = f2bf(v);
  } else {
    int idx = (bid - FA2_BLOCKS - PW1_BLOCKS) * 256 + t;
    int r = idx & 15, ht = (idx >> 4) & 1, g = (idx >> 5) & 1, f = idx >> 6;
    w2p[idx] = W2[f * NH + ht * 32 + (r & 3) + 8 * (r >> 2) + 4 * g];
  }
}

__device__ __forceinline__ v2f pk_fma(v2f a, v2f b, v2f c) {   // verified R5-R11
  v2f d;
  asm("v_pk_fma_f32 %0, %1, %2, %3" : "=v"(d) : "v"(a), "v"(b), "v"(c));
  return d;
}

__device__ __forceinline__ float xor32_add(float v) {   // verified R4-R11
  v2i p = __builtin_amdgcn_permlane32_swap(__float_as_int(v), __float_as_int(v), false, false);
  return __int_as_float(p.x) + __int_as_float(p.y);
}

// layer-2 (R10/R11-verified math): relu + dot(W2) + lane^32 reduce
__device__ __forceinline__ float layer2(const f32x16& a0, const f32x16& a1,
                                        const float4* __restrict__ wp2) {
  v2f psA = {0.f,0.f}, psB = {0.f,0.f}, psC = {0.f,0.f}, psD = {0.f,0.f};
#pragma unroll
  for (int rq = 0; rq < 4; ++rq) {
    float4 w0 = wp2[rq], w1 = wp2[4 + rq];
    v2f m;
    m[0] = fmaxf(a0[rq * 4 + 0], 0.f); m[1] = fmaxf(a0[rq * 4 + 1], 0.f);
    if (rq & 1) psB = pk_fma(m, (v2f){w0.x, w0.y}, psB);
    else        psA = pk_fma(m, (v2f){w0.x, w0.y}, psA);
    m[0] = fmaxf(a0[rq * 4 + 2], 0.f); m[1] = fmaxf(a0[rq * 4 + 3], 0.f);
    if (rq & 1) psB = pk_fma(m, (v2f){w0.z, w0.w}, psB);
    else        psA = pk_fma(m, (v2f){w0.z, w0.w}, psA);
    m[0] = fmaxf(a1[rq * 4 + 0], 0.f); m[1] = fmaxf(a1[rq * 4 + 1], 0.f);
    if (rq & 1) psD = pk_fma(m, (v2f){w1.x, w1.y}, psD);
    else        psC = pk_fma(m, (v2f){w1.x, w1.y}, psC);
    m[0] = fmaxf(a1[rq * 4 + 2], 0.f); m[1] = fmaxf(a1[rq * 4 + 3], 0.f);
    if (rq & 1) psD = pk_fma(m, (v2f){w1.z, w1.w}, psD);
    else        psC = pk_fma(m, (v2f){w1.z, w1.w}, psC);
  }
  v2f ts = (psA + psB) + (psC + psD);
  return xor32_add(ts[0] + ts[1]);
}

// f-outer, zero-LDS/zero-barrier; 4 MFMA chains before any layer-2 (ILP).
__global__ __launch_bounds__(256, 3) void fused_mlp_kernel(
    const unsigned short* __restrict__ fa2, const unsigned short* __restrict__ w1p,
    const float* __restrict__ w2p, float* __restrict__ ws) {
  const int t = threadIdx.x;
  const int wv = t >> 6;
  const int l = t & 63;
  const int g = l >> 5;
  const int lc = l & 31;
  const int gf = blockIdx.x >> 7;        // f-pair 0..15
  const int nb = blockIdx.x & 127;       // b-range; XCD = nb%8 for all gf -> fa2 L2 reuse

  // ---- W1 frags -> registers, ONCE (48 VGPR) ----
  frag_ab wf[2][2][3];
#pragma unroll
  for (int f2 = 0; f2 < 2; ++f2)
#pragma unroll
    for (int ht = 0; ht < 2; ++ht)
#pragma unroll
      for (int kt = 0; kt < 3; ++kt)
        wf[f2][ht][kt] = *(const frag_ab*)(w1p + ((((gf * 2 + f2) * 6 + ht * 3 + kt) * 64 + l) * 8));

  const float4* wp2_0 = (const float4*)w2p + ((gf * 2 + 0) * 2 + g) * 8;
  const float4* wp2_1 = (const float4*)w2p + ((gf * 2 + 1) * 2 + g) * 8;

  const f32x16 zero16 = {0.f,0.f,0.f,0.f,0.f,0.f,0.f,0.f,0.f,0.f,0.f,0.f,0.f,0.f,0.f,0.f};
  const long bt0 = (long)nb * 32 + wv * 8;

  frag_ab cur[3], nxt[3];
#pragma unroll
  for (int kt = 0; kt < 3; ++kt)
    cur[kt] = *(const frag_ab*)(fa2 + ((bt0 * 3 + kt) * 64 + l) * 8);

#pragma unroll
  for (int it = 0; it < 8; ++it) {
    if (it < 7) {   // 1-deep prefetch (L2-resident)
#pragma unroll
      for (int kt = 0; kt < 3; ++kt)
        nxt[kt] = *(const frag_ab*)(fa2 + (((bt0 + it + 1) * 3 + kt) * 64 + l) * 8);
    }

    // ---- all 4 independent MFMA chains first (f2 x ht, depth 3 each) ----
    f32x16 A0 = zero16, A1 = zero16, B0 = zero16, B1 = zero16;
#pragma unroll
    for (int kt = 0; kt < 3; ++kt) {
      A0 = __builtin_amdgcn_mfma_f32_32x32x16_bf16(wf[0][0][kt], cur[kt], A0, 0, 0, 0);
      A1 = __builtin_amdgcn_mfma_f32_32x32x16_bf16(wf[0][1][kt], cur[kt], A1, 0, 0, 0);
      B0 = __builtin_amdgcn_mfma_f32_32x32x16_bf16(wf[1][0][kt], cur[kt], B0, 0, 0, 0);
      B1 = __builtin_amdgcn_mfma_f32_32x32x16_bf16(wf[1][1][kt], cur[kt], B1, 0, 0, 0);
    }

    // ---- then both layer-2 blocks (VALU), overlappable with other waves' MFMAs ----
    float r0 = layer2(A0, A1, wp2_0);
    float r1 = layer2(B0, B1, wp2_1);

    if (g == 0) {   // block-private contiguous slice (no cross-block lines)
      const long b = (bt0 + it) * 32 + lc;
      float2 o; o.x = r0; o.y = r1;
      *(float2*)(ws + ((long)gf * B_TOTAL + b) * 2) = o;
    }

#pragma unroll
    for (int kt = 0; kt < 3; ++kt) cur[kt] = nxt[kt];
  }
}

// R9/R10-verified (UNCHANGED): out[b][f] = ws[f>>1][b][f&1] + b2[f] + ft[b][f]
__global__ void add_kernel(const float* __restrict__ ws, const float* __restrict__ ft,
                           const float* __restrict__ b2, float* __restrict__ out) {
  int flat = blockIdx.x * 256 + threadIdx.x;   // B*8 total
  int f4 = flat & 7;
  long b = flat >> 3;
  const float2* s0 = (const float2*)ws + (long)(2 * f4) * B_TOTAL + b;
  const float2* s1 = (const float2*)ws + (long)(2 * f4 + 1) * B_TOTAL + b;
  float2 v0 = *s0, v1 = *s1;
  float4 x  = *(const float4*)(ft + b * NF + f4 * 4);
  float4 bb = *(const float4*)(b2 + f4 * 4);
  float4 o;
  o.x = v0.x + bb.x + x.x;
  o.y = v0.y + bb.y + x.y;
  o.z = v1.x + bb.z + x.z;
  o.w = v1.y + bb.w + x.w;
  *(float4*)(out + b * NF + f4 * 4) = o;
}

extern "C" void kernel_launch(void* const* d_in, const int* in_sizes, int n_in,
                              void* d_out, int out_size, void* d_ws, size_t ws_size,
                              hipStream_t stream) {
  const float* ft = (const float*)d_in[0];
  const float* at = (const float*)d_in[1];
  const float* W1 = (const float*)d_in[2];
  const float* b1 = (const float*)d_in[3];
  const float* W2 = (const float*)d_in[4];
  const float* b2 = (const float*)d_in[5];
  float* out = (float*)d_out;

  unsigned short* w1p = (unsigned short*)d_ws;                       // 192 KB
  float* w2p = (float*)((char*)d_ws + (1u << 18));                   // 16 KB  @ 256 KB
  unsigned short* fa2 = (unsigned short*)((char*)d_ws + (1u << 19)); // 12.6 MB @ 512 KB
  float* ws  = (float*)((char*)d_ws + (14u << 20));                  // 16.7 MB @ 14 MB

  prep_kernel<<<FA2_BLOCKS + PW1_BLOCKS + PW2_BLOCKS, 256, 0, stream>>>(
      W1, b1, W2, ft, at, w1p, w2p, fa2);
  fused_mlp_kernel<<<2048, 256, 0, stream>>>(fa2, w1p, w2p, ws);
  add_kernel<<<B_TOTAL * 8 / 256, 256, 0, stream>>>(ws, ft, b2, out);
}